// Round 6
// baseline (37.291 us; speedup 1.0000x reference)
//
#include <hip/hip_runtime.h>
#include <math.h>

// Problem constants (fixed by the reference setup)
#define NN 16
#define CC 85
#define HH 160
#define WW 160
#define HW_ 25600            // H*W
#define NHW 409600           // N*H*W
#define TB 256
#define GRIDN 400            // NHW/4/TB: one float4 cell per thread

struct Sync {                // first 256 B of d_ws, zeroed by hipMemsetAsync
  double sum_liou;
  double sum_nll;
  double obj_corr;
  int cnt_f;
  int c1, c2, cdone;
  int nperb[NN];
};

__device__ __forceinline__ float wave_sum(float v) {
#pragma unroll
  for (int o = 32; o; o >>= 1) v += __shfl_down(v, o, 64);
  return v;
}

__device__ __forceinline__ float sl1(float d) {
  float ad = fabsf(d);
  return (ad < 1.f) ? 0.5f * d * d : (ad - 0.5f);
}

// SIoU variant from the reference (_bbox_iou)
__device__ __forceinline__ float siou(float pcx, float pcy, float pw, float ph,
                                      float gcx, float gcy, float gw, float gh) {
  const float eps = 1e-7f;
  float b1x1 = pcx - pw * 0.5f, b1x2 = pcx + pw * 0.5f;
  float b1y1 = pcy - ph * 0.5f, b1y2 = pcy + ph * 0.5f;
  float b2x1 = gcx - gw * 0.5f, b2x2 = gcx + gw * 0.5f;
  float b2y1 = gcy - gh * 0.5f, b2y2 = gcy + gh * 0.5f;
  float inter = fmaxf(fminf(b1x2, b2x2) - fmaxf(b1x1, b2x1), 0.f) *
                fmaxf(fminf(b1y2, b2y2) - fmaxf(b1y1, b2y1), 0.f);
  float w1 = b1x2 - b1x1, h1 = b1y2 - b1y1 + eps;
  float w2 = b2x2 - b2x1, h2 = b2y2 - b2y1 + eps;
  float uni = w1 * h1 + w2 * h2 - inter + eps;
  float iou = inter / uni;
  float cw = fmaxf(b1x2, b2x2) - fminf(b1x1, b2x1);
  float ch = fmaxf(b1y2, b2y2) - fminf(b1y1, b2y1);
  float s_cw = (b2x1 + b2x2 - b1x1 - b1x2) * 0.5f;
  float s_ch = (b2y1 + b2y2 - b1y1 - b1y2) * 0.5f;
  float sigma = sqrtf(s_cw * s_cw + s_ch * s_ch);
  float sin_a1 = fabsf(s_cw) / sigma;
  float sin_a2 = fabsf(s_ch) / sigma;
  float sin_a = (sin_a1 > 0.70710678f) ? sin_a2 : sin_a1;
  // cos(2*asin(x) - pi/2) == 2*x*sqrt(1-x^2)
  float angle_cost = 2.f * sin_a * sqrtf(fmaxf(1.f - sin_a * sin_a, 0.f));
  float rx = s_cw / cw; rx *= rx;
  float ry = s_ch / ch; ry *= ry;
  float gamma = angle_cost - 2.f;
  float dist = 2.f - expf(gamma * rx) - expf(gamma * ry);
  float ow = fabsf(w1 - w2) / fmaxf(w1, w2);
  float oh = fabsf(h1 - h2) / fmaxf(h1, h2);
  float e1 = 1.f - expf(-ow), e2 = 1.f - expf(-oh);
  float s1 = e1 * e1; s1 *= s1;
  float s2 = e2 * e2; s2 *= s2;
  return iou - 0.5f * (dist + s1 + s2);
}

// Single fused kernel, grid=400 (full TLP for the memory-heavy Phase A).
// Deadlock-safety of the spin barrier: only blocks with anchors (bid<64)
// ever spin; the other 336 blocks increment c1 and EXIT, freeing their CUs,
// so all 400 increments arrive even at 1 block/CU residency.
__global__ __launch_bounds__(TB)
void fused(const float* __restrict__ preds, const float* __restrict__ targets,
           int M, Sync* __restrict__ sy, int* __restrict__ winner,
           float* __restrict__ part_obj, float* __restrict__ part_iou,
           float* __restrict__ part_cnt, float* __restrict__ out) {
  const int tid = threadIdx.x, bid = blockIdx.x;
  const int t = bid * TB + tid;
  const int lane = tid & 63, wid = tid >> 6;
  const int M4 = 4 * M;
  const int NACT = (M4 + TB - 1) / TB;   // 64 anchor blocks

  __shared__ float shA0[4], shA1[4], shA2[4];
  __shared__ float shM0[4], shM1[4], shO[4];
  __shared__ float shB0[4], shB1[4], shB2[4], shR[4];
  __shared__ int hist[NN];

  // ================= Phase A (all 400 blocks) =================
  // one float4 cell per thread: base obj term (tobj=0, factor=0.75 folded out)
  float objs;
  {
    int i0 = t * 4;
    int b = i0 / HW_;
    int r = i0 - b * HW_;                        // HW_ % 4 == 0
    float4 p4 = *reinterpret_cast<const float4*>(preds + (size_t)b * CC * HW_ + r);
    objs = sl1(p4.x) + sl1(p4.y) + sl1(p4.z) + sl1(p4.w);
  }

  // anchors: decode + 6 gathers + SIoU + nll; state stays in REGISTERS
  float iou_v = 0.f, mf = 0.f, pobj = 0.f, nllv = 0.f;
  int ab = 0, aidx = 0;
  bool am = false;
  if (t < M4) {
    int mm = t % M, q = t / M;
    const float* t6 = targets + (size_t)mm * 6;
    ab = (int)t6[0];
    int acls = (int)t6[1];
    float gx = t6[2] * (float)WW, gy = t6[3] * (float)HH;
    float gw = t6[4] * (float)WW, gh = t6[5] * (float)HH;
    int gi = (int)gx + (q & 1);
    int gj = (int)gy + (q >> 1);
    am = (gi >= 1) && (gi < WW) && (gj >= 1) && (gj < HH);
    if (am) {
      const float* p = preds + (size_t)ab * CC * HW_ + (size_t)gj * WW + gi;
      pobj = p[0];
      float p1 = p[(size_t)1 * HW_];
      float p2 = p[(size_t)2 * HW_];
      float p3 = p[(size_t)3 * HW_];
      float p4v = p[(size_t)4 * HW_];
      float pc = p[(size_t)(5 + acls) * HW_];
      float px = tanhf(p1) + (float)gi;
      float py = tanhf(p2) + (float)gj;
      float pw = (1.f / (1.f + expf(-p3))) * (float)WW;
      float ph = (1.f / (1.f + expf(-p4v))) * (float)HH;
      iou_v = siou(px, py, pw, ph, gx, gy, gw, gh);
      nllv = -logf(pc);
      mf = 1.f;
      aidx = ab * HW_ + gj * WW + gi;
      winner[aidx] = -1;                 // scatter init: only cells used later
    }
  }

  {
    float o = wave_sum(objs), s = wave_sum(iou_v), c = wave_sum(mf);
    if (lane == 0) { shA0[wid] = o; shA1[wid] = s; shA2[wid] = c; }
    __syncthreads();
    if (tid == 0) {
      part_obj[bid] = shA0[0] + shA0[1] + shA0[2] + shA0[3];
      part_iou[bid] = shA1[0] + shA1[1] + shA1[2] + shA1[3];
      part_cnt[bid] = shA2[0] + shA2[1] + shA2[2] + shA2[3];
    }
  }

  // ---- barrier arrive (all blocks); non-anchor blocks exit ----
  __syncthreads();
  if (tid < NN) hist[tid] = 0;           // zero LDS hist before the wait-sync
  if (tid == 0) {
    __threadfence();
    __hip_atomic_fetch_add(&sy->c1, 1, __ATOMIC_RELEASE, __HIP_MEMORY_SCOPE_AGENT);
  }
  const bool active = (bid * TB) < M4;   // uniform per block
  if (!active) return;

  if (tid == 0) {
    while (__hip_atomic_load(&sy->c1, __ATOMIC_ACQUIRE, __HIP_MEMORY_SCOPE_AGENT) < GRIDN)
      __builtin_amdgcn_s_sleep(1);
  }
  __syncthreads();   // all threads in block now see all parts + winner inits

  // ================= Phase B (64 anchor blocks) =================
  // iou_mean: fixed-order reduce of 400 partials (identical in every block)
  float s = 0.f, c = 0.f;
  for (int i = tid; i < GRIDN; i += TB) { s += part_iou[i]; c += part_cnt[i]; }
  s = wave_sum(s); c = wave_sum(c);
  if (lane == 0) { shM0[wid] = s; shM1[wid] = c; }
  __syncthreads();
  float iou_mean = (shM0[0] + shM0[1] + shM0[2] + shM0[3]) /
                   fmaxf(shM1[0] + shM1[1] + shM1[2] + shM1[3], 1.f);

  float obj_base = 0.f;
  if (bid == 0) {   // block 0 folds the base-obj partials (kept in a register)
    float v = 0.f;
    for (int i = tid; i < GRIDN; i += TB) v += part_obj[i];
    v = wave_sum(v);
    if (lane == 0) shO[wid] = v;
    __syncthreads();
    obj_base = shO[0] + shO[1] + shO[2] + shO[3];
  }

  bool af = false;
  float fc = 0.f, liou = 0.f, nl = 0.f;
  if (am && iou_v > iou_mean) {
    af = true;
    fc = 1.f;
    liou = 1.f - iou_v;
    nl = nllv;
    atomicMax(&winner[aidx], t);        // max-t == numpy last-occurrence-wins
    atomicAdd(&hist[ab], 1);
  }
  {
    float a = wave_sum(fc), b2 = wave_sum(liou), d2 = wave_sum(nl);
    if (lane == 0) { shB0[wid] = a; shB1[wid] = b2; shB2[wid] = d2; }
    __syncthreads();
    if (tid == 0) {
      atomicAdd(&sy->cnt_f, (int)(shB0[0] + shB0[1] + shB0[2] + shB0[3]));
      atomicAdd(&sy->sum_liou, (double)(shB1[0] + shB1[1] + shB1[2] + shB1[3]));
      atomicAdd(&sy->sum_nll, (double)(shB2[0] + shB2[1] + shB2[2] + shB2[3]));
    }
    if (tid < NN && hist[tid] > 0)
      atomicAdd(&sy->nperb[tid], hist[tid]);
  }

  // ---- barrier over the 64 anchor blocks ----
  __syncthreads();
  if (tid == 0) {
    __threadfence();
    __hip_atomic_fetch_add(&sy->c2, 1, __ATOMIC_RELEASE, __HIP_MEMORY_SCOPE_AGENT);
    while (__hip_atomic_load(&sy->c2, __ATOMIC_ACQUIRE, __HIP_MEMORY_SCOPE_AGENT) < NACT)
      __builtin_amdgcn_s_sleep(1);
  }
  __syncthreads();

  // ================= Phase C: winner correction + finalize =================
  float corr = 0.f;
  if (af && winner[aidx] == t) {
    float fval = (float)HW_ / (float)sy->nperb[ab] * 0.25f;
    corr = sl1(pobj - iou_v) * fval - sl1(pobj) * 0.75f;
  }
  float r = wave_sum(corr);
  if (lane == 0) shR[wid] = r;
  __syncthreads();
  if (tid == 0) {
    atomicAdd(&sy->obj_corr, (double)(shR[0] + shR[1] + shR[2] + shR[3]));
    __threadfence();
    __hip_atomic_fetch_add(&sy->cdone, 1, __ATOMIC_RELEASE, __HIP_MEMORY_SCOPE_AGENT);
    if (bid == 0) {
      while (__hip_atomic_load(&sy->cdone, __ATOMIC_ACQUIRE, __HIP_MEMORY_SCOPE_AGENT) < NACT)
        __builtin_amdgcn_s_sleep(1);
      float cf = fmaxf((float)sy->cnt_f, 1.f);
      float iou_loss = (float)sy->sum_liou / cf;
      float cls_loss = (float)sy->sum_nll / cf;
      float obj_loss = (float)((0.75 * (double)obj_base + sy->obj_corr) / (double)NHW);
      out[0] = iou_loss;
      out[1] = obj_loss;
      out[2] = cls_loss;
      out[3] = iou_loss * 8.f + obj_loss * 16.f + cls_loss;
    }
  }
}

extern "C" void kernel_launch(void* const* d_in, const int* in_sizes, int n_in,
                              void* d_out, int out_size, void* d_ws, size_t ws_size,
                              hipStream_t stream) {
  const float* preds = (const float*)d_in[0];
  const float* targets = (const float*)d_in[1];
  int M = in_sizes[1] / 6;     // 4096

  char* ws = (char*)d_ws;
  Sync* sy = (Sync*)ws;                                 // 256 B (memset)
  size_t off = 256;
  int* winner = (int*)(ws + off);       off += (size_t)NHW * 4;   // 1.6 MB
  float* part_obj = (float*)(ws + off); off += GRIDN * 4;
  float* part_iou = (float*)(ws + off); off += GRIDN * 4;
  float* part_cnt = (float*)(ws + off); off += GRIDN * 4;

  // Counters must start at 0 every call: first timed replay sees 0xAA poison,
  // later replays see leftovers — in-kernel self-reset can't cover both.
  hipMemsetAsync(ws, 0, 256, stream);
  fused<<<GRIDN, TB, 0, stream>>>(preds, targets, M, sy, winner,
                                  part_obj, part_iou, part_cnt, (float*)d_out);
}

// Round 7
// 26.632 us; speedup vs baseline: 1.4002x; 1.4002x over previous
//
#include <hip/hip_runtime.h>
#include <math.h>

// Problem constants (fixed by the reference setup)
#define NN 16
#define CC 85
#define HH 160
#define WW 160
#define HW_ 25600            // H*W
#define NHW 409600           // N*H*W
#define TB 256
#define GRIDN 400            // NHW/4/TB: one float4 cell per thread
#define MAGIC1 0x4D414731    // phase-A done
#define MAGIC2 0x4D414732    // phase-B done
#define MAGIC3 0x4D414733    // phase-C done

__device__ __forceinline__ float wave_sum(float v) {
#pragma unroll
  for (int o = 32; o; o >>= 1) v += __shfl_down(v, o, 64);
  return v;
}

__device__ __forceinline__ float sl1(float d) {
  float ad = fabsf(d);
  return (ad < 1.f) ? 0.5f * d * d : (ad - 0.5f);
}

// SIoU variant from the reference (_bbox_iou)
__device__ __forceinline__ float siou(float pcx, float pcy, float pw, float ph,
                                      float gcx, float gcy, float gw, float gh) {
  const float eps = 1e-7f;
  float b1x1 = pcx - pw * 0.5f, b1x2 = pcx + pw * 0.5f;
  float b1y1 = pcy - ph * 0.5f, b1y2 = pcy + ph * 0.5f;
  float b2x1 = gcx - gw * 0.5f, b2x2 = gcx + gw * 0.5f;
  float b2y1 = gcy - gh * 0.5f, b2y2 = gcy + gh * 0.5f;
  float inter = fmaxf(fminf(b1x2, b2x2) - fmaxf(b1x1, b2x1), 0.f) *
                fmaxf(fminf(b1y2, b2y2) - fmaxf(b1y1, b2y1), 0.f);
  float w1 = b1x2 - b1x1, h1 = b1y2 - b1y1 + eps;
  float w2 = b2x2 - b2x1, h2 = b2y2 - b2y1 + eps;
  float uni = w1 * h1 + w2 * h2 - inter + eps;
  float iou = inter / uni;
  float cw = fmaxf(b1x2, b2x2) - fminf(b1x1, b2x1);
  float ch = fmaxf(b1y2, b2y2) - fminf(b1y1, b2y1);
  float s_cw = (b2x1 + b2x2 - b1x1 - b1x2) * 0.5f;
  float s_ch = (b2y1 + b2y2 - b1y1 - b1y2) * 0.5f;
  float sigma = sqrtf(s_cw * s_cw + s_ch * s_ch);
  float sin_a1 = fabsf(s_cw) / sigma;
  float sin_a2 = fabsf(s_ch) / sigma;
  float sin_a = (sin_a1 > 0.70710678f) ? sin_a2 : sin_a1;
  // cos(2*asin(x) - pi/2) == 2*x*sqrt(1-x^2)
  float angle_cost = 2.f * sin_a * sqrtf(fmaxf(1.f - sin_a * sin_a, 0.f));
  float rx = s_cw / cw; rx *= rx;
  float ry = s_ch / ch; ry *= ry;
  float gamma = angle_cost - 2.f;
  float dist = 2.f - expf(gamma * rx) - expf(gamma * ry);
  float ow = fabsf(w1 - w2) / fmaxf(w1, w2);
  float oh = fabsf(h1 - h2) / fmaxf(h1, h2);
  float e1 = 1.f - expf(-ow), e2 = 1.f - expf(-oh);
  float s1 = e1 * e1; s1 *= s1;
  float s2 = e2 * e2; s2 *= s2;
  return iou - 0.5f * (dist + s1 + s2);
}

// Spin until flags[0..n) == magic. Agent-scope acquire loads (L1-coherent).
__device__ __forceinline__ void wait_all(const int* f, int n, int magic) {
  for (;;) {
    int ok = 1;
    for (int i = threadIdx.x; i < n; i += TB)
      if (__hip_atomic_load(&f[i], __ATOMIC_ACQUIRE, __HIP_MEMORY_SCOPE_AGENT) != magic)
        ok = 0;
    if (__syncthreads_and(ok)) return;
    __builtin_amdgcn_s_sleep(4);
  }
}

// Caller must __syncthreads() first (drains the whole block's stores to L2).
__device__ __forceinline__ void signal(int* f, int magic) {
  if (threadIdx.x == 0)
    __hip_atomic_store(f, magic, __ATOMIC_RELEASE, __HIP_MEMORY_SCOPE_AGENT);
}

// Single kernel, zero pre-initialized state:
//  - barriers = magic-flag arrays (work from ANY initial contents; block 0
//    clears them at the end for subsequent replays)
//  - all reductions via per-block partials written unconditionally each call
//  - winner array scatter-initialized each call for exactly the cells used
// Deadlock safety: only anchor blocks (bid<64) spin on anchor-block flags;
// cell-only blocks signal and exit (freeing CUs); block 0 awaits everyone.
__global__ __launch_bounds__(TB)
void fused(const float* __restrict__ preds, const float* __restrict__ targets,
           int M, int* __restrict__ winner,
           int* __restrict__ flags1, int* __restrict__ flags2,
           int* __restrict__ flags3,
           float* __restrict__ partA_iou, float* __restrict__ partA_cnt,
           float* __restrict__ part_obj,
           float* __restrict__ partB_cnt, float* __restrict__ partB_liou,
           float* __restrict__ partB_nll, int* __restrict__ hist16,
           float* __restrict__ partC, float* __restrict__ out) {
  const int tid = threadIdx.x, bid = blockIdx.x;
  const int t = bid * TB + tid;
  const int lane = tid & 63, wid = tid >> 6;
  const int M4 = 4 * M;
  const int nact = (M4 + TB - 1) / TB;       // 64 anchor blocks
  const bool anchorblk = bid < nact;

  __shared__ float sh0[4], sh1[4], sh2[4];
  __shared__ int hist[NN];
  __shared__ int hist_tot[NN];

  // ================= Phase A (all 400 blocks) =================
  // one float4 cell per thread: base obj term (tobj=0, factor=0.75 folded out)
  float objs;
  {
    int i0 = t * 4;
    int b = i0 / HW_;
    int r = i0 - b * HW_;                    // HW_ % 4 == 0
    float4 p4 = *reinterpret_cast<const float4*>(preds + (size_t)b * CC * HW_ + r);
    objs = sl1(p4.x) + sl1(p4.y) + sl1(p4.z) + sl1(p4.w);
  }

  // anchors (blocks 0..63): decode + 6 gathers + SIoU; state stays in REGISTERS
  float iou_v = 0.f, mf = 0.f, pobj = 0.f, nllv = 0.f;
  int ab = 0, aidx = 0;
  bool am = false;
  if (anchorblk && t < M4) {
    int mm = t % M, q = t / M;
    const float* t6 = targets + (size_t)mm * 6;
    ab = (int)t6[0];
    int acls = (int)t6[1];
    float gx = t6[2] * (float)WW, gy = t6[3] * (float)HH;
    float gw = t6[4] * (float)WW, gh = t6[5] * (float)HH;
    int gi = (int)gx + (q & 1);
    int gj = (int)gy + (q >> 1);
    am = (gi >= 1) && (gi < WW) && (gj >= 1) && (gj < HH);
    if (am) {
      const float* p = preds + (size_t)ab * CC * HW_ + (size_t)gj * WW + gi;
      pobj = p[0];
      float p1 = p[(size_t)1 * HW_];
      float p2 = p[(size_t)2 * HW_];
      float p3 = p[(size_t)3 * HW_];
      float p4v = p[(size_t)4 * HW_];
      float pc = p[(size_t)(5 + acls) * HW_];
      float px = tanhf(p1) + (float)gi;
      float py = tanhf(p2) + (float)gj;
      float pw = (1.f / (1.f + expf(-p3))) * (float)WW;
      float ph = (1.f / (1.f + expf(-p4v))) * (float)HH;
      iou_v = siou(px, py, pw, ph, gx, gy, gw, gh);
      nllv = -logf(pc);
      mf = 1.f;
      aidx = ab * HW_ + gj * WW + gi;
      winner[aidx] = -1;                     // scatter-init only cells used
    }
  }

  if (tid < NN) hist[tid] = 0;               // LDS hist for Phase B
  {
    float o = wave_sum(objs), s = wave_sum(iou_v), c = wave_sum(mf);
    if (lane == 0) { sh0[wid] = o; sh1[wid] = s; sh2[wid] = c; }
  }
  __syncthreads();
  if (tid == 0) {
    part_obj[bid] = sh0[0] + sh0[1] + sh0[2] + sh0[3];
    if (anchorblk) {
      partA_iou[bid] = sh1[0] + sh1[1] + sh1[2] + sh1[3];
      partA_cnt[bid] = sh2[0] + sh2[1] + sh2[2] + sh2[3];
    }
  }
  __syncthreads();                           // drain all stores (incl. winner inits)
  signal(&flags1[bid], MAGIC1);
  if (!anchorblk) return;                    // cell blocks done — free the CU

  // bar1: only the 64 anchor blocks' Phase-A results are needed here
  wait_all(flags1, nact, MAGIC1);

  // ================= Phase B (anchor blocks) =================
  // iou_mean: fixed-order reduce of the 64 anchor partials (wave 0 holds data)
  {
    float si = (tid < nact) ? partA_iou[tid] : 0.f;
    float sc = (tid < nact) ? partA_cnt[tid] : 0.f;
    si = wave_sum(si); sc = wave_sum(sc);
    if (tid == 0) { sh0[0] = si; sh1[0] = sc; }
  }
  __syncthreads();
  float iou_mean = sh0[0] / fmaxf(sh1[0], 1.f);
  __syncthreads();                           // everyone read before sh reuse

  bool af = false;
  float fc = 0.f, liou = 0.f, nl = 0.f;
  if (am && iou_v > iou_mean) {
    af = true;
    fc = 1.f;
    liou = 1.f - iou_v;
    nl = nllv;
    atomicMax(&winner[aidx], t);             // max-t == numpy last-wins
    atomicAdd(&hist[ab], 1);
  }
  {
    float a = wave_sum(fc), b2 = wave_sum(liou), d2 = wave_sum(nl);
    if (lane == 0) { sh0[wid] = a; sh1[wid] = b2; sh2[wid] = d2; }
  }
  __syncthreads();
  if (tid == 0) {
    partB_cnt[bid]  = sh0[0] + sh0[1] + sh0[2] + sh0[3];
    partB_liou[bid] = sh1[0] + sh1[1] + sh1[2] + sh1[3];
    partB_nll[bid]  = sh2[0] + sh2[1] + sh2[2] + sh2[3];
  }
  if (tid < NN) hist16[bid * NN + tid] = hist[tid];
  __syncthreads();
  signal(&flags2[bid], MAGIC2);
  wait_all(flags2, nact, MAGIC2);

  // ================= Phase C (anchor blocks) =================
  // nperb: deterministic reduce of hist16[64][16]
  if (tid < NN) hist_tot[tid] = 0;
  __syncthreads();
  {
    int h = 0;
    for (int b2 = tid >> 4; b2 < nact; b2 += 16) h += hist16[b2 * NN + (tid & 15)];
    atomicAdd(&hist_tot[tid & 15], h);       // LDS, integer -> deterministic
  }
  __syncthreads();

  float corr = 0.f;
  if (af) {
    int w = __hip_atomic_load(&winner[aidx], __ATOMIC_RELAXED,
                              __HIP_MEMORY_SCOPE_AGENT);  // L1-bypass
    if (w == t) {
      float fval = (float)HW_ / (float)hist_tot[ab] * 0.25f;
      corr = sl1(pobj - iou_v) * fval - sl1(pobj) * 0.75f;
    }
  }
  {
    float r = wave_sum(corr);
    if (lane == 0) sh0[wid] = r;
  }
  __syncthreads();
  if (tid == 0) partC[bid] = sh0[0] + sh0[1] + sh0[2] + sh0[3];
  __syncthreads();
  signal(&flags3[bid], MAGIC3);
  if (bid != 0) return;

  // ================= Finalize (block 0) =================
  wait_all(flags3, nact, MAGIC3);            // anchor pipeline done
  wait_all(flags1, GRIDN, MAGIC1);           // cell blocks' part_obj ready
  {
    float v = 0.f;
    for (int i = tid; i < GRIDN; i += TB) v += part_obj[i];
    v = wave_sum(v);
    if (lane == 0) sh0[wid] = v;
  }
  __syncthreads();
  {
    float cf = (tid < nact) ? partB_cnt[tid] : 0.f;
    float li = (tid < nact) ? partB_liou[tid] : 0.f;
    float nv = (tid < nact) ? partB_nll[tid] : 0.f;
    float co = (tid < nact) ? partC[tid] : 0.f;
    cf = wave_sum(cf); li = wave_sum(li); nv = wave_sum(nv); co = wave_sum(co);
    if (tid == 0) {
      float obj_base = sh0[0] + sh0[1] + sh0[2] + sh0[3];
      float cff = fmaxf(cf, 1.f);
      float iou_loss = li / cff;
      float cls_loss = nv / cff;
      float obj_loss = (0.75f * obj_base + co) / (float)NHW;
      out[0] = iou_loss;
      out[1] = obj_loss;
      out[2] = cls_loss;
      out[3] = iou_loss * 8.f + obj_loss * 16.f + cls_loss;
    }
  }
  // clear flags so the NEXT replay starts from != MAGIC (all other blocks
  // have provably exited: their last action was their flag store)
  __syncthreads();
  for (int i = tid; i < GRIDN; i += TB) flags1[i] = 0;
  if (tid < nact) { flags2[tid] = 0; flags3[tid] = 0; }
}

extern "C" void kernel_launch(void* const* d_in, const int* in_sizes, int n_in,
                              void* d_out, int out_size, void* d_ws, size_t ws_size,
                              hipStream_t stream) {
  const float* preds = (const float*)d_in[0];
  const float* targets = (const float*)d_in[1];
  int M = in_sizes[1] / 6;     // 4096

  char* ws = (char*)d_ws;
  int*   flags1    = (int*)(ws + 0);        // 400 * 4 = 1600 B
  int*   flags2    = (int*)(ws + 2048);     // 64
  int*   flags3    = (int*)(ws + 2304);     // 64
  float* partA_iou = (float*)(ws + 2560);   // 64
  float* partA_cnt = (float*)(ws + 2816);   // 64
  float* part_obj  = (float*)(ws + 3072);   // 400 * 4 = 1600 B
  float* partB_cnt = (float*)(ws + 4736);   // 64
  float* partB_liou= (float*)(ws + 4992);   // 64
  float* partB_nll = (float*)(ws + 5248);   // 64
  int*   hist16    = (int*)(ws + 5504);     // 64*16*4 = 4096 B
  float* partC     = (float*)(ws + 9600);   // 64
  int*   winner    = (int*)(ws + 10240);    // NHW * 4 = 1.6 MB

  fused<<<GRIDN, TB, 0, stream>>>(preds, targets, M, winner,
                                  flags1, flags2, flags3,
                                  partA_iou, partA_cnt, part_obj,
                                  partB_cnt, partB_liou, partB_nll,
                                  hist16, partC, (float*)d_out);
}